// Round 1
// baseline (232.781 us; speedup 1.0000x reference)
//
#include <hip/hip_runtime.h>
#include <hip/hip_bf16.h>

// LengthRegulator: B=32, T=512, C=384, MAX_LEN=4096 (fixed by setup_inputs).
// out[b,p,:] = x[b, t(p), :] where t(p) = #{j : csum[b,j] <= p}, clipped to T-1,
// zeroed for p >= mel_len[b] = csum[b,T-1]. mel_len appended as float32.

#define B  32
#define T  512
#define C  384
#define C4 96          // C / 4
#define ML 4096
#define PPB 128        // positions per block in expand kernel

// ---- Kernel 1: per-batch inclusive prefix sum of max(dur,0) --------------
__global__ void lr_scan_kernel(const int* __restrict__ dur,
                               int* __restrict__ csum,
                               float* __restrict__ mel_out) {
    __shared__ int s[T];
    const int b = blockIdx.x;
    const int t = threadIdx.x;       // blockDim.x == T == 512

    int v = dur[b * T + t];
    if (v < 0) v = 0;
    s[t] = v;
    __syncthreads();

    // Hillis-Steele inclusive scan over 512 elements
    for (int off = 1; off < T; off <<= 1) {
        int add = (t >= off) ? s[t - off] : 0;
        __syncthreads();
        s[t] += add;
        __syncthreads();
    }

    csum[b * T + t] = s[t];
    if (t == T - 1) mel_out[b] = (float)s[T - 1];
}

// ---- Kernel 2: expansion --------------------------------------------------
__global__ __launch_bounds__(256)
void lr_expand_kernel(const float* __restrict__ x,
                      const int* __restrict__ csum,
                      float* __restrict__ out) {
    __shared__ int s_cs[T];
    __shared__ int s_idx[PPB];

    const int tilesPerBatch = ML / PPB;            // 32
    const int b     = blockIdx.x / tilesPerBatch;
    const int ptile = blockIdx.x % tilesPerBatch;
    const int tid   = threadIdx.x;                 // blockDim.x == 256

    // stage csum[b] into LDS (512 ints)
    for (int i = tid; i < T; i += 256) s_cs[i] = csum[b * T + i];
    __syncthreads();

    const int mel = s_cs[T - 1];

    // one binary search per position in this tile
    if (tid < PPB) {
        const int p = ptile * PPB + tid;
        int r = -1;                                // -1 => write zeros
        if (p < mel) {
            int lo = 0, hi = T;                    // first index with cs[i] > p
            while (lo < hi) {
                int mid = (lo + hi) >> 1;
                if (s_cs[mid] <= p) lo = mid + 1; else hi = mid;
            }
            r = lo < (T - 1) ? lo : (T - 1);       // clip (defensive; p<mel => lo<T)
        }
        s_idx[tid] = r;
    }
    __syncthreads();

    const float4* __restrict__ x4 = (const float4*)x;
    float4* __restrict__ o4 = (float4*)out;
    const size_t xrow_base = (size_t)b * T * C4;
    const size_t obase = (size_t)b * ML * C4 + (size_t)ptile * PPB * C4;

    const float4 zero = make_float4(0.f, 0.f, 0.f, 0.f);
    // PPB*C4 = 12288 float4s; 48 iterations of 256 threads, fully coalesced
    #pragma unroll 4
    for (int v = tid; v < PPB * C4; v += 256) {
        const int pl = v / C4;                     // const div -> magic mul
        const int c4 = v - pl * C4;
        const int t  = s_idx[pl];
        float4 val = zero;
        if (t >= 0) val = x4[xrow_base + (size_t)t * C4 + c4];
        o4[obase + v] = val;
    }
}

extern "C" void kernel_launch(void* const* d_in, const int* in_sizes, int n_in,
                              void* d_out, int out_size, void* d_ws, size_t ws_size,
                              hipStream_t stream) {
    const float* x   = (const float*)d_in[0];
    const int*   dur = (const int*)d_in[1];
    // d_in[2] = max_len scalar on device; value is fixed at 4096 for this bench.

    float* out     = (float*)d_out;                       // B*ML*C floats
    float* mel_out = out + (size_t)B * ML * C;            // 32 floats (tail)
    int*   csum    = (int*)d_ws;                          // B*T ints = 64 KB

    lr_scan_kernel<<<B, T, 0, stream>>>(dur, csum, mel_out);

    const int grid = B * (ML / PPB);                      // 1024 blocks
    lr_expand_kernel<<<grid, 256, 0, stream>>>(x, csum, out);
}